// Round 11
// baseline (5750.528 us; speedup 1.0000x reference)
//
#include <hip/hip_runtime.h>
#include <hip/hip_bf16.h>
#include <cstddef>

// MHAttention forward, MI355X/gfx950.
// Dtype contract (R0-R3): inputs fp32 (toks, W*, b*; masks int32), OUTPUT fp32.
// Internals: bf16 MFMA fragments, fp32 accumulation.
// R10 -> R11: attn ~48% stall = __syncthreads vmcnt(0) drains (m97 pathology)
// + split-b64 DS ops. Changes:
//  (a) in-loop barriers -> s_waitcnt lgkmcnt(0) + raw s_barrier (cross-wave
//      data is LDS-only; staging global loads need not drain);
//  (b) staging prefetch distance 2 (two reg banks);
//  (c) STR 68->72: all frags 16B-aligned -> b128 DS ops (~40->20 per wave/iter);
//  (d) Q/P share one LDS region (Q is prologue-only) -> 46 KB, 3 blocks/CU;
//  (e) proj_kv -> m97-style 256-thread staged GEMM (toks chunk in LDS shared
//      by 4 waves, 1 lgkm-barrier/chunk, ~32 waves/CU).

typedef __bf16 bf16_8 __attribute__((ext_vector_type(8)));
typedef float f32x4 __attribute__((ext_vector_type(4)));
typedef short s16x4 __attribute__((ext_vector_type(4)));
typedef short s16x8 __attribute__((ext_vector_type(8)));

#define HID 768
#define NHEADS 12
#define HD 64
#define BATCH 4
#define SEQ 2048
#define NEGBIG2 (-1.44269504e31f)  // -1e31 * log2e, exp2 -> 0
#define SCALE2 0.18033688f         // 0.125 * log2e

#define KT 64            // keys per LDS tile (attn)
#define NKT (SEQ / KT)
#define STR 72           // attn LDS row stride: 144B rows, 16B-aligned frags, 2-way banks
#define ASTR 40          // proj LDS row stride: 80B rows, 16B-aligned frags

static __device__ __forceinline__ f32x4 mfma16x16x32(bf16_8 a, bf16_8 b, f32x4 c) {
  return __builtin_amdgcn_mfma_f32_16x16x32_bf16(a, b, c, 0, 0, 0);
}

// workgroup barrier that waits LDS ops only (NOT outstanding global prefetch).
// 0xc07f = lgkmcnt(0), vmcnt/expcnt = max (no wait).
static __device__ __forceinline__ void lds_barrier() {
  __builtin_amdgcn_s_waitcnt(0xc07f);
  __builtin_amdgcn_s_barrier();
}

static __device__ __forceinline__ float fast_exp2(float x) {
#if __has_builtin(__builtin_amdgcn_exp2f)
  return __builtin_amdgcn_exp2f(x);
#else
  return __expf(x * 0.69314718f);
#endif
}

static __device__ __forceinline__ s16x4 pack_bf16x4(f32x4 p) {
  s16x4 o;
#pragma unroll
  for (int i = 0; i < 4; ++i) {
    __bf16 b = (__bf16)p[i];
    o[i] = __builtin_bit_cast(short, b);
  }
  return o;
}

static __device__ __forceinline__ bf16_8 cvt_a_frag(const float* p) {
  f32x4 af0 = *(const f32x4*)p;
  f32x4 af1 = *(const f32x4*)(p + 4);
  bf16_8 a;
  a[0] = (__bf16)af0[0]; a[1] = (__bf16)af0[1];
  a[2] = (__bf16)af0[2]; a[3] = (__bf16)af0[3];
  a[4] = (__bf16)af1[0]; a[5] = (__bf16)af1[1];
  a[6] = (__bf16)af1[2]; a[7] = (__bf16)af1[3];
  return a;
}

// ---------- mask -> additive kadd2 (0 or -1e31*log2e), fp32, global ----------
__global__ __launch_bounds__(256) void mask_kadd(const int* __restrict__ masks,
                                                 float* __restrict__ kaddG) {
  int i = blockIdx.x * 256 + threadIdx.x;
  kaddG[i] = masks[i] ? 0.0f : NEGBIG2;
}

// ---------- 3x 768x768 transpose + fp32->bf16, one launch (z picks matrix) ----------
__global__ __launch_bounds__(256) void transpose768x3(const float* __restrict__ Wq,
                                                      const float* __restrict__ Wk,
                                                      const float* __restrict__ Wv,
                                                      __bf16* __restrict__ WtBase) {
  const float* in = blockIdx.z == 0 ? Wq : (blockIdx.z == 1 ? Wk : Wv);
  __bf16* out = WtBase + (size_t)blockIdx.z * HID * HID;
  __shared__ __bf16 tile[32][33];
  int bx = blockIdx.x * 32, by = blockIdx.y * 32;
  int tx = threadIdx.x, ty = threadIdx.y;  // block (32,8)
#pragma unroll
  for (int r = 0; r < 32; r += 8)
    tile[ty + r][tx] = (__bf16)in[(size_t)(by + ty + r) * HID + bx + tx];
  __syncthreads();
#pragma unroll
  for (int r = 0; r < 32; r += 8)
    out[(size_t)(bx + ty + r) * HID + by + tx] = tile[tx][ty + r];
}

// ---------- K+V projection, m97-style: 256 threads, 64 rows x 64 cols (1 head) ----------
// toks chunk (64 rows x 32 k) staged in LDS (bf16, double-buffered), shared by
// 4 waves; wave w owns output cols w*16..+16 for BOTH K and V.
__global__ __launch_bounds__(256, 4) void proj_kv(const float* __restrict__ toks,
                                                  const __bf16* __restrict__ WtK,
                                                  const float* __restrict__ bk,
                                                  const __bf16* __restrict__ WtV,
                                                  const float* __restrict__ bv,
                                                  __bf16* __restrict__ Kout,
                                                  __bf16* __restrict__ Vtout,
                                                  int head0, int hm) {
  __shared__ __align__(16) __bf16 ldsA[2][64 * ASTR];  // 2 x 5120 B
  int tid = threadIdx.x;
  int w = tid >> 6, lane = tid & 63, l16 = lane & 15, quad = lane >> 4;
  int m0 = blockIdx.x * 64;
  int hl = blockIdx.y, h = head0 + hl;
  int srow = tid >> 2, scg = tid & 3;  // staging: row 0..63, 8-elem group 0..3
  const float* asrc = toks + (size_t)(m0 + srow) * HID + scg * 8;
  const __bf16* bKrow = WtK + (size_t)(h * 64 + w * 16 + l16) * HID + quad * 8;
  const __bf16* bVrow = WtV + (size_t)(h * 64 + w * 16 + l16) * HID + quad * 8;
  f32x4 zero = {0.f, 0.f, 0.f, 0.f};
  f32x4 aK[4], aV[4];
#pragma unroll
  for (int mt = 0; mt < 4; ++mt) { aK[mt] = zero; aV[mt] = zero; }

  // stage chunk 0
  *(bf16_8*)(&ldsA[0][srow * ASTR + scg * 8]) = cvt_a_frag(asrc);
  __syncthreads();

  const int NCH = HID / 32;  // 24
  for (int t = 0; t < NCH; ++t) {
    int b = t & 1;
    int kk = t * 32;
    // prefetch chunk t+1 (fp32, consumed by ds_write at bottom)
    bf16_8 areg;
    if (t + 1 < NCH) areg = cvt_a_frag(asrc + kk + 32);
    // B frags for this wave's 16 cols (L2-hot weights)
    bf16_8 bkf = *(const bf16_8*)(bKrow + kk);
    bf16_8 bvf = *(const bf16_8*)(bVrow + kk);
#pragma unroll
    for (int mt = 0; mt < 4; ++mt) {
      // A frag: lane holds toks[m = mt*16+l16][k = quad*8+j]
      bf16_8 af = *(const bf16_8*)(&ldsA[b][(mt * 16 + l16) * ASTR + quad * 8]);
      aK[mt] = mfma16x16x32(af, bkf, aK[mt]);
      aV[mt] = mfma16x16x32(af, bvf, aV[mt]);
    }
    if (t + 1 < NCH) {
      *(bf16_8*)(&ldsA[b ^ 1][srow * ASTR + scg * 8]) = areg;
      lds_barrier();
    }
  }

  int d = w * 16 + l16;
  float bnK = bk[h * 64 + d];
  float bnV = bv[h * 64 + d];
#pragma unroll
  for (int mt = 0; mt < 4; ++mt) {
#pragma unroll
    for (int r = 0; r < 4; ++r) {
      int m = m0 + mt * 16 + quad * 4 + r;
      int b = m >> 11;            // batch (64-row tiles never cross batch)
      int s = m & (SEQ - 1);
      Kout[(((size_t)b * hm + hl) * SEQ + s) * HD + d] = (__bf16)(aK[mt][r] + bnK);
      Vtout[(((size_t)b * hm + hl) * HD + d) * SEQ + s] = (__bf16)(aV[mt][r] + bnV);
    }
  }
}

// ---------- fused Q-proj + flash attention, staged LDS + lgkm-only barriers ----------
// Block 256 threads (4 waves) per (bh, 64-query tile). 64-key K/V tiles double-
// buffered in LDS; staging prefetch distance 2 (reg banks). Wave w: Q-proj rows
// w*16..+16; QK^T (S^T = K*Q^T) for key-block w vs all 64 q; PV for d-block w.
// Q and P share one LDS region (Q consumed into regs in prologue).
__global__ __launch_bounds__(256, 3) void attn_fused(const float* __restrict__ toks,
                                                     const __bf16* __restrict__ WtQ,
                                                     const float* __restrict__ bq,
                                                     const __bf16* __restrict__ Kbuf,
                                                     const __bf16* __restrict__ Vtbuf,
                                                     const float* __restrict__ kaddG,
                                                     float* __restrict__ out,
                                                     int head0, int hm) {
  __shared__ __align__(16) __bf16 ldsK[2][64 * STR];  // 2 x 9216 B
  __shared__ __align__(16) __bf16 ldsV[2][64 * STR];  // 2 x 9216 B
  __shared__ __align__(16) __bf16 ldsQP[64 * STR];    // 9216 B (Q prologue, then P)
  int tid = threadIdx.x;
  int w = tid >> 6, lane = tid & 63, l16 = lane & 15, quad = lane >> 4;
  int bz = blockIdx.z, hl = blockIdx.y, h = head0 + hl;
  int q0 = blockIdx.x * 64;
  const float* kb = kaddG + (size_t)bz * SEQ;
  f32x4 zero = {0.f, 0.f, 0.f, 0.f};

  const __bf16* Kb = Kbuf + ((size_t)bz * hm + hl) * SEQ * HD;
  const __bf16* Vb = Vtbuf + ((size_t)bz * hm + hl) * HD * SEQ;

  // --- Q projection: wave w -> rows q0 + w*16 .. +16, all 64 d ---
  {
    const float* arow = toks + ((size_t)bz * SEQ + q0 + w * 16 + l16) * HID + quad * 8;
    const __bf16* brow = WtQ + (size_t)(h * 64 + l16) * HID + quad * 8;
    f32x4 qa[4] = {zero, zero, zero, zero};
    for (int kk = 0; kk < HID; kk += 32) {
      bf16_8 a = cvt_a_frag(arow + kk);
#pragma unroll
      for (int t = 0; t < 4; ++t)
        qa[t] = mfma16x16x32(a, *(const bf16_8*)(brow + (size_t)t * 16 * HID + kk), qa[t]);
    }
#pragma unroll
    for (int t = 0; t < 4; ++t) {
      float bn = bq[h * 64 + t * 16 + l16];
#pragma unroll
      for (int r = 0; r < 4; ++r)
        ldsQP[(w * 16 + quad * 4 + r) * STR + t * 16 + l16] = (__bf16)(qa[t][r] + bn);
    }
  }

  // --- stage tile 0 directly; preload tile 1 into reg bank 1 ---
  int srow = tid >> 3, sc = tid & 7;  // srow 0..31 (+32), 8-elem chunk 0..7
  s16x8 stg[2][4];                    // [bank][k0,k1,v0,v1], distance-2 prefetch
  {
    s16x8 k0 = *(const s16x8*)(Kb + (size_t)srow * HD + sc * 8);
    s16x8 k1 = *(const s16x8*)(Kb + (size_t)(srow + 32) * HD + sc * 8);
    s16x8 v0 = *(const s16x8*)(Vb + (size_t)srow * SEQ + sc * 8);
    s16x8 v1 = *(const s16x8*)(Vb + (size_t)(srow + 32) * SEQ + sc * 8);
    *(s16x8*)(&ldsK[0][srow * STR + sc * 8]) = k0;
    *(s16x8*)(&ldsK[0][(srow + 32) * STR + sc * 8]) = k1;
    *(s16x8*)(&ldsV[0][srow * STR + sc * 8]) = v0;
    *(s16x8*)(&ldsV[0][(srow + 32) * STR + sc * 8]) = v1;
    stg[1][0] = *(const s16x8*)(Kb + (size_t)(KT + srow) * HD + sc * 8);
    stg[1][1] = *(const s16x8*)(Kb + (size_t)(KT + srow + 32) * HD + sc * 8);
    stg[1][2] = *(const s16x8*)(Vb + (size_t)srow * SEQ + KT + sc * 8);
    stg[1][3] = *(const s16x8*)(Vb + (size_t)(srow + 32) * SEQ + KT + sc * 8);
  }
  __syncthreads();  // Q + tile 0 visible

  // Q B-frags for ALL 4 q-subtiles: lane holds Q[q = s*16+l16][d = half*32+quad*8+j]
  bf16_8 qf[4][2];
#pragma unroll
  for (int s = 0; s < 4; ++s)
#pragma unroll
    for (int half = 0; half < 2; ++half)
      qf[s][half] = *(const bf16_8*)(&ldsQP[(s * 16 + l16) * STR + half * 32 + quad * 8]);
  float actq[4];
#pragma unroll
  for (int s = 0; s < 4; ++s) actq[s] = (kb[q0 + s * 16 + l16] == 0.0f) ? 1.0f : 0.0f;
  __syncthreads();  // Q fully consumed by all waves before P aliases the region

  float lsum[4] = {0.f, 0.f, 0.f, 0.f};
  f32x4 acc[4];
#pragma unroll
  for (int s = 0; s < 4; ++s) acc[s] = zero;

  for (int t = 0; t < NKT; ++t) {
    int buf = t & 1;
    int j0 = t * KT;
    // issue loads for tile t+2 into reg bank (t&1) [bank is dead: its tile went
    // to LDS last iteration]. Clamp index; values unused past the end.
    {
      int j2 = (t + 2 < NKT) ? (t + 2) * KT : 0;
      stg[buf][0] = *(const s16x8*)(Kb + (size_t)(j2 + srow) * HD + sc * 8);
      stg[buf][1] = *(const s16x8*)(Kb + (size_t)(j2 + srow + 32) * HD + sc * 8);
      stg[buf][2] = *(const s16x8*)(Vb + (size_t)srow * SEQ + j2 + sc * 8);
      stg[buf][3] = *(const s16x8*)(Vb + (size_t)(srow + 32) * SEQ + j2 + sc * 8);
    }
    // --- QK^T: this wave's key block (keys j0 + w*16 .. +16) vs all 64 q ---
    bf16_8 kf0 = *(const bf16_8*)(&ldsK[buf][(w * 16 + l16) * STR + quad * 8]);
    bf16_8 kf1 = *(const bf16_8*)(&ldsK[buf][(w * 16 + l16) * STR + 32 + quad * 8]);
    f32x4 ck = *(const f32x4*)(kb + j0 + w * 16 + quad * 4);
#pragma unroll
    for (int s = 0; s < 4; ++s) {
      // S^T tile: lane holds S^T[key = w*16 + quad*4 + r][q = s*16 + l16]
      f32x4 st = mfma16x16x32(kf1, qf[s][1], mfma16x16x32(kf0, qf[s][0], zero));
      f32x4 p;
#pragma unroll
      for (int r = 0; r < 4; ++r) {
        // masked key: fma -> -1.44e31, exp2 -> 0. inactive q: actq=0 -> logit 0 (= ref).
        float v = actq[s] * fmaf(st[r], SCALE2, ck[r]);
        p[r] = fast_exp2(v);
      }
      lsum[s] += p[0] + p[1] + p[2] + p[3];
      *(s16x4*)(&ldsQP[(s * 16 + l16) * STR + w * 16 + quad * 4]) = pack_bf16x4(p);
    }
    lds_barrier();  // B1: P complete across waves; K reads done (LDS-only wait)

    // --- PV: this wave's d block (d = w*16 .. +16) vs all 64 keys ---
#pragma unroll
    for (int kc = 0; kc < 2; ++kc) {
      bf16_8 vf = *(const bf16_8*)(&ldsV[buf][(w * 16 + l16) * STR + kc * 32 + quad * 8]);
#pragma unroll
      for (int s = 0; s < 4; ++s) {
        bf16_8 pf = *(const bf16_8*)(&ldsQP[(s * 16 + l16) * STR + kc * 32 + quad * 8]);
        acc[s] = mfma16x16x32(pf, vf, acc[s]);
      }
    }
    // write tile t+1 (reg bank (t+1)&1, loaded at iter t-1: latency long gone)
    {
      int nb = buf ^ 1;
      *(s16x8*)(&ldsK[nb][srow * STR + sc * 8]) = stg[nb][0];
      *(s16x8*)(&ldsK[nb][(srow + 32) * STR + sc * 8]) = stg[nb][1];
      *(s16x8*)(&ldsV[nb][srow * STR + sc * 8]) = stg[nb][2];
      *(s16x8*)(&ldsV[nb][(srow + 32) * STR + sc * 8]) = stg[nb][3];
    }
    lds_barrier();  // B2: tile t+1 visible; P free for overwrite
  }

  // --- lsum: quad-sum in-wave, cross-wave via LDS (ldsQP reused) ---
  __syncthreads();
  float* ls = (float*)ldsQP;
#pragma unroll
  for (int s = 0; s < 4; ++s) {
    float v = lsum[s];
    v += __shfl_xor(v, 16);
    v += __shfl_xor(v, 32);
    if (quad == 0) ls[(w * 4 + s) * 16 + l16] = v;
  }
  __syncthreads();
  float lr[4][4];
#pragma unroll
  for (int s = 0; s < 4; ++s) {
    float tot = ls[(0 * 4 + s) * 16 + l16] + ls[(1 * 4 + s) * 16 + l16] +
                ls[(2 * 4 + s) * 16 + l16] + ls[(3 * 4 + s) * 16 + l16];
    float linv = 1.0f / tot;
#pragma unroll
    for (int r = 0; r < 4; ++r) lr[s][r] = __shfl(linv, quad * 4 + r);
  }
#pragma unroll
  for (int s = 0; s < 4; ++s)
#pragma unroll
    for (int r = 0; r < 4; ++r)
      out[((size_t)bz * SEQ + q0 + s * 16 + quad * 4 + r) * HID + h * HD + w * 16 + l16] =
          acc[s][r] * lr[s][r];
}

extern "C" void kernel_launch(void* const* d_in, const int* in_sizes, int n_in,
                              void* d_out, int out_size, void* d_ws, size_t ws_size,
                              hipStream_t stream) {
  (void)in_sizes; (void)n_in; (void)out_size;
  const float* toks = (const float*)d_in[0];
  const int* masks = (const int*)d_in[1];
  const float* Wq = (const float*)d_in[2];
  const float* bq = (const float*)d_in[3];
  const float* Wk = (const float*)d_in[4];
  const float* bk = (const float*)d_in[5];
  const float* Wv = (const float*)d_in[6];
  const float* bv = (const float*)d_in[7];
  char* ws = (char*)d_ws;
  const size_t KADD_B = (size_t)BATCH * SEQ * 4;
  const size_t WT_B = (size_t)HID * HID * 2;
  const size_t KV_FULL_B = (size_t)BATCH * NHEADS * SEQ * HD * 2;
  const size_t KV_HEAD_B = (size_t)BATCH * SEQ * HD * 2;
  const size_t TIER_A_NEED = KADD_B + 3 * WT_B + 2 * KV_FULL_B;  // ~28.7 MB
  float* kaddG = (float*)(ws);
  __bf16* WtQ = (__bf16*)(ws + KADD_B + 0 * WT_B);
  __bf16* WtK = (__bf16*)(ws + KADD_B + 1 * WT_B);
  __bf16* WtV = (__bf16*)(ws + KADD_B + 2 * WT_B);
  float* outp = (float*)d_out;

  mask_kadd<<<BATCH * SEQ / 256, 256, 0, stream>>>(masks, kaddG);
  dim3 tgrid(HID / 32, HID / 32, 3), tblk(32, 8);
  transpose768x3<<<tgrid, tblk, 0, stream>>>(Wq, Wk, Wv, WtQ);

  if (ws_size >= TIER_A_NEED) {
    __bf16* Kf = (__bf16*)(ws + KADD_B + 3 * WT_B);
    __bf16* Vtf = (__bf16*)(ws + KADD_B + 3 * WT_B + KV_FULL_B);
    dim3 pgrid(BATCH * SEQ / 64, NHEADS);
    proj_kv<<<pgrid, 256, 0, stream>>>(toks, WtK, bk, WtV, bv, Kf, Vtf, 0, NHEADS);
    dim3 agrid(SEQ / 64, NHEADS, BATCH);
    attn_fused<<<agrid, 256, 0, stream>>>(toks, WtQ, bq, Kf, Vtf, kaddG, outp, 0, NHEADS);
  } else {
    __bf16* Kh = (__bf16*)(ws + KADD_B + 3 * WT_B);
    __bf16* Vth = (__bf16*)(ws + KADD_B + 3 * WT_B + KV_HEAD_B);
    dim3 pgrid(BATCH * SEQ / 64, 1);
    dim3 agrid(SEQ / 64, 1, BATCH);
    for (int h = 0; h < NHEADS; ++h) {
      proj_kv<<<pgrid, 256, 0, stream>>>(toks, WtK, bk, WtV, bv, Kh, Vth, h, 1);
      attn_fused<<<agrid, 256, 0, stream>>>(toks, WtQ, bq, Kh, Vth, kaddG, outp, h, 1);
    }
  }
}

// Round 12
// 303.064 us; speedup vs baseline: 18.9746x; 18.9746x over previous
//
#include <hip/hip_runtime.h>
#include <hip/hip_bf16.h>
#include <cstddef>

// MHAttention forward, MI355X/gfx950.
// Dtype contract (R0-R3): inputs fp32 (toks, W*, b*; masks int32), OUTPUT fp32.
// Internals: bf16 MFMA fragments, fp32 accumulation.
// R11 -> R12 post-mortem: R11's stg[buf] runtime indexing demoted the prefetch
// bank to SCRATCH -> per-iter scratch round-trips whose vmcnt waits drained the
// global prefetch queue every iteration (30x regression). The lgkm-only barrier
// was confounded, not falsified. R12 = R10's proven attn structure (distance-1
// staging in NAMED registers, STR=68 b64 LDS ops = 0 conflicts) with exactly
// two deltas: (a) in-loop barriers are s_waitcnt lgkmcnt(0)+s_barrier via
// inline asm (no vmcnt drain); (b) Q/P share one LDS region (43.5 KB).
// proj_kv keeps R11's m97-style staged form (proj phase measured ~45 us).

typedef __bf16 bf16_8 __attribute__((ext_vector_type(8)));
typedef float f32x4 __attribute__((ext_vector_type(4)));
typedef short s16x4 __attribute__((ext_vector_type(4)));
typedef short s16x8 __attribute__((ext_vector_type(8)));

#define HID 768
#define NHEADS 12
#define HD 64
#define BATCH 4
#define SEQ 2048
#define NEGBIG2 (-1.44269504e31f)  // -1e31 * log2e, exp2 -> 0
#define SCALE2 0.18033688f         // 0.125 * log2e

#define KT 64            // keys per LDS tile (attn)
#define NKT (SEQ / KT)
#define STR 68           // attn LDS row stride (elems): 136B rows -> 0 conflicts (R10)
#define ASTR 40          // proj LDS row stride (elems): 80B rows, 16B-aligned frags

static __device__ __forceinline__ f32x4 mfma16x16x32(bf16_8 a, bf16_8 b, f32x4 c) {
  return __builtin_amdgcn_mfma_f32_16x16x32_bf16(a, b, c, 0, 0, 0);
}

// Workgroup barrier waiting LDS ops only — does NOT drain outstanding global
// loads (vmcnt). "memory" clobber pins compiler-level ordering of LDS ops.
static __device__ __forceinline__ void lds_barrier() {
  __asm__ volatile("s_waitcnt lgkmcnt(0)\n\ts_barrier" ::: "memory");
}

static __device__ __forceinline__ float fast_exp2(float x) {
#if __has_builtin(__builtin_amdgcn_exp2f)
  return __builtin_amdgcn_exp2f(x);
#else
  return __expf(x * 0.69314718f);
#endif
}

static __device__ __forceinline__ s16x4 pack_bf16x4(f32x4 p) {
  s16x4 o;
#pragma unroll
  for (int i = 0; i < 4; ++i) {
    __bf16 b = (__bf16)p[i];
    o[i] = __builtin_bit_cast(short, b);
  }
  return o;
}

// two b64 LDS reads -> one bf16_8 fragment (rows are 8B-aligned at STR=68)
static __device__ __forceinline__ bf16_8 cat2(const __bf16* p) {
  s16x4 lo = *(const s16x4*)p;
  s16x4 hi = *(const s16x4*)(p + 4);
  s16x8 v = __builtin_shufflevector(lo, hi, 0, 1, 2, 3, 4, 5, 6, 7);
  return __builtin_bit_cast(bf16_8, v);
}

// one 16B register chunk -> two b64 LDS writes
static __device__ __forceinline__ void write2(__bf16* p, s16x8 v) {
  *(s16x4*)p = __builtin_shufflevector(v, v, 0, 1, 2, 3);
  *(s16x4*)(p + 4) = __builtin_shufflevector(v, v, 4, 5, 6, 7);
}

static __device__ __forceinline__ bf16_8 cvt_a_frag(const float* p) {
  f32x4 af0 = *(const f32x4*)p;
  f32x4 af1 = *(const f32x4*)(p + 4);
  bf16_8 a;
  a[0] = (__bf16)af0[0]; a[1] = (__bf16)af0[1];
  a[2] = (__bf16)af0[2]; a[3] = (__bf16)af0[3];
  a[4] = (__bf16)af1[0]; a[5] = (__bf16)af1[1];
  a[6] = (__bf16)af1[2]; a[7] = (__bf16)af1[3];
  return a;
}

// ---------- mask -> additive kadd2 (0 or -1e31*log2e), fp32, global ----------
__global__ __launch_bounds__(256) void mask_kadd(const int* __restrict__ masks,
                                                 float* __restrict__ kaddG) {
  int i = blockIdx.x * 256 + threadIdx.x;
  kaddG[i] = masks[i] ? 0.0f : NEGBIG2;
}

// ---------- 3x 768x768 transpose + fp32->bf16, one launch (z picks matrix) ----------
__global__ __launch_bounds__(256) void transpose768x3(const float* __restrict__ Wq,
                                                      const float* __restrict__ Wk,
                                                      const float* __restrict__ Wv,
                                                      __bf16* __restrict__ WtBase) {
  const float* in = blockIdx.z == 0 ? Wq : (blockIdx.z == 1 ? Wk : Wv);
  __bf16* out = WtBase + (size_t)blockIdx.z * HID * HID;
  __shared__ __bf16 tile[32][33];
  int bx = blockIdx.x * 32, by = blockIdx.y * 32;
  int tx = threadIdx.x, ty = threadIdx.y;  // block (32,8)
#pragma unroll
  for (int r = 0; r < 32; r += 8)
    tile[ty + r][tx] = (__bf16)in[(size_t)(by + ty + r) * HID + bx + tx];
  __syncthreads();
#pragma unroll
  for (int r = 0; r < 32; r += 8)
    out[(size_t)(bx + ty + r) * HID + by + tx] = tile[tx][ty + r];
}

// ---------- K+V projection, m97-style: 256 threads, 64 rows x 64 cols (1 head) ----------
// toks chunk (64 rows x 32 k) staged in LDS (bf16, double-buffered), shared by
// 4 waves; wave w owns output cols w*16..+16 for BOTH K and V.
__global__ __launch_bounds__(256, 4) void proj_kv(const float* __restrict__ toks,
                                                  const __bf16* __restrict__ WtK,
                                                  const float* __restrict__ bk,
                                                  const __bf16* __restrict__ WtV,
                                                  const float* __restrict__ bv,
                                                  __bf16* __restrict__ Kout,
                                                  __bf16* __restrict__ Vtout,
                                                  int head0, int hm) {
  __shared__ __align__(16) __bf16 ldsA[2][64 * ASTR];  // 2 x 5120 B
  int tid = threadIdx.x;
  int w = tid >> 6, lane = tid & 63, l16 = lane & 15, quad = lane >> 4;
  int m0 = blockIdx.x * 64;
  int hl = blockIdx.y, h = head0 + hl;
  int srow = tid >> 2, scg = tid & 3;  // staging: row 0..63, 8-elem group 0..3
  const float* asrc = toks + (size_t)(m0 + srow) * HID + scg * 8;
  const __bf16* bKrow = WtK + (size_t)(h * 64 + w * 16 + l16) * HID + quad * 8;
  const __bf16* bVrow = WtV + (size_t)(h * 64 + w * 16 + l16) * HID + quad * 8;
  f32x4 zero = {0.f, 0.f, 0.f, 0.f};
  f32x4 aK[4], aV[4];
#pragma unroll
  for (int mt = 0; mt < 4; ++mt) { aK[mt] = zero; aV[mt] = zero; }

  // stage chunk 0
  *(bf16_8*)(&ldsA[0][srow * ASTR + scg * 8]) = cvt_a_frag(asrc);
  __syncthreads();

  const int NCH = HID / 32;  // 24
  for (int t = 0; t < NCH; ++t) {
    int b = t & 1;
    int kk = t * 32;
    // prefetch chunk t+1 (named register, consumed by ds_write at bottom)
    bf16_8 areg;
    if (t + 1 < NCH) areg = cvt_a_frag(asrc + kk + 32);
    // B frags for this wave's 16 cols (L2-hot weights)
    bf16_8 bkf = *(const bf16_8*)(bKrow + kk);
    bf16_8 bvf = *(const bf16_8*)(bVrow + kk);
#pragma unroll
    for (int mt = 0; mt < 4; ++mt) {
      // A frag: lane holds toks[m = mt*16+l16][k = quad*8+j]
      bf16_8 af = *(const bf16_8*)(&ldsA[b][(mt * 16 + l16) * ASTR + quad * 8]);
      aK[mt] = mfma16x16x32(af, bkf, aK[mt]);
      aV[mt] = mfma16x16x32(af, bvf, aV[mt]);
    }
    if (t + 1 < NCH) {
      *(bf16_8*)(&ldsA[b ^ 1][srow * ASTR + scg * 8]) = areg;
      lds_barrier();
    }
  }

  int d = w * 16 + l16;
  float bnK = bk[h * 64 + d];
  float bnV = bv[h * 64 + d];
#pragma unroll
  for (int mt = 0; mt < 4; ++mt) {
#pragma unroll
    for (int r = 0; r < 4; ++r) {
      int m = m0 + mt * 16 + quad * 4 + r;
      int b = m >> 11;            // batch (64-row tiles never cross batch)
      int s = m & (SEQ - 1);
      Kout[(((size_t)b * hm + hl) * SEQ + s) * HD + d] = (__bf16)(aK[mt][r] + bnK);
      Vtout[(((size_t)b * hm + hl) * HD + d) * SEQ + s] = (__bf16)(aV[mt][r] + bnV);
    }
  }
}

// ---------- fused Q-proj + flash attention: R10 structure + lgkm-only barriers ----------
// Block 256 threads (4 waves) per (bh, 64-query tile). 64-key K/V tiles double-
// buffered in LDS; staging loads for t+1 at body top into NAMED registers,
// ds_write at body bottom (distance-1, no arrays -> no scratch). Wave w: Q-proj
// rows w*16..+16; QK^T (S^T = K*Q^T) key-block w vs all 64 q; PV d-block w.
// Q and P share one LDS region (Q consumed into regs in prologue).
__global__ __launch_bounds__(256, 3) void attn_fused(const float* __restrict__ toks,
                                                     const __bf16* __restrict__ WtQ,
                                                     const float* __restrict__ bq,
                                                     const __bf16* __restrict__ Kbuf,
                                                     const __bf16* __restrict__ Vtbuf,
                                                     const float* __restrict__ kaddG,
                                                     float* __restrict__ out,
                                                     int head0, int hm) {
  __shared__ __align__(16) __bf16 ldsK[2][64 * STR];  // 2 x 8704 B
  __shared__ __align__(16) __bf16 ldsV[2][64 * STR];  // 2 x 8704 B
  __shared__ __align__(16) __bf16 ldsQP[64 * STR];    // 8704 B (Q prologue, then P)
  int tid = threadIdx.x;
  int w = tid >> 6, lane = tid & 63, l16 = lane & 15, quad = lane >> 4;
  int bz = blockIdx.z, hl = blockIdx.y, h = head0 + hl;
  int q0 = blockIdx.x * 64;
  const float* kb = kaddG + (size_t)bz * SEQ;
  f32x4 zero = {0.f, 0.f, 0.f, 0.f};

  const __bf16* Kb = Kbuf + ((size_t)bz * hm + hl) * SEQ * HD;
  const __bf16* Vb = Vtbuf + ((size_t)bz * hm + hl) * HD * SEQ;

  // --- Q projection: wave w -> rows q0 + w*16 .. +16, all 64 d ---
  {
    const float* arow = toks + ((size_t)bz * SEQ + q0 + w * 16 + l16) * HID + quad * 8;
    const __bf16* brow = WtQ + (size_t)(h * 64 + l16) * HID + quad * 8;
    f32x4 qa[4] = {zero, zero, zero, zero};
    for (int kk = 0; kk < HID; kk += 32) {
      bf16_8 a = cvt_a_frag(arow + kk);
#pragma unroll
      for (int t = 0; t < 4; ++t)
        qa[t] = mfma16x16x32(a, *(const bf16_8*)(brow + (size_t)t * 16 * HID + kk), qa[t]);
    }
#pragma unroll
    for (int t = 0; t < 4; ++t) {
      float bn = bq[h * 64 + t * 16 + l16];
#pragma unroll
      for (int r = 0; r < 4; ++r)
        ldsQP[(w * 16 + quad * 4 + r) * STR + t * 16 + l16] = (__bf16)(qa[t][r] + bn);
    }
  }

  // --- stage tile 0 (K rows = keys, V rows = d; 16B/chunk via 2 b64 writes) ---
  int srow = tid >> 3, sc = tid & 7;  // srow 0..31 (+32), 8-elem chunk 0..7
  {
    s16x8 k0 = *(const s16x8*)(Kb + (size_t)srow * HD + sc * 8);
    s16x8 k1 = *(const s16x8*)(Kb + (size_t)(srow + 32) * HD + sc * 8);
    s16x8 v0 = *(const s16x8*)(Vb + (size_t)srow * SEQ + sc * 8);
    s16x8 v1 = *(const s16x8*)(Vb + (size_t)(srow + 32) * SEQ + sc * 8);
    write2(&ldsK[0][srow * STR + sc * 8], k0);
    write2(&ldsK[0][(srow + 32) * STR + sc * 8], k1);
    write2(&ldsV[0][srow * STR + sc * 8], v0);
    write2(&ldsV[0][(srow + 32) * STR + sc * 8], v1);
  }
  __syncthreads();  // Q + tile 0 visible

  // Q B-frags for ALL 4 q-subtiles: lane holds Q[q = s*16+l16][d = half*32+quad*8+j]
  bf16_8 qf[4][2];
#pragma unroll
  for (int s = 0; s < 4; ++s)
#pragma unroll
    for (int half = 0; half < 2; ++half)
      qf[s][half] = cat2(&ldsQP[(s * 16 + l16) * STR + half * 32 + quad * 8]);
  float actq[4];
#pragma unroll
  for (int s = 0; s < 4; ++s) actq[s] = (kb[q0 + s * 16 + l16] == 0.0f) ? 1.0f : 0.0f;
  __syncthreads();  // Q fully consumed by all waves before P aliases the region

  float lsum[4] = {0.f, 0.f, 0.f, 0.f};
  f32x4 acc[4];
#pragma unroll
  for (int s = 0; s < 4; ++s) acc[s] = zero;

  for (int t = 0; t < NKT; ++t) {
    int j0 = t * KT;
    int jn = (t + 1 < NKT) ? j0 + KT : 0;  // wrap: valid addr, values unused
    int buf = t & 1, nbuf = buf ^ 1;
    // stage loads for t+1 into NAMED registers (consumed by ds_write at bottom)
    s16x8 k0 = *(const s16x8*)(Kb + (size_t)(jn + srow) * HD + sc * 8);
    s16x8 k1 = *(const s16x8*)(Kb + (size_t)(jn + srow + 32) * HD + sc * 8);
    s16x8 v0 = *(const s16x8*)(Vb + (size_t)srow * SEQ + jn + sc * 8);
    s16x8 v1 = *(const s16x8*)(Vb + (size_t)(srow + 32) * SEQ + jn + sc * 8);

    // --- QK^T: this wave's key block (keys j0 + w*16 .. +16) vs all 64 q ---
    bf16_8 kf0 = cat2(&ldsK[buf][(w * 16 + l16) * STR + quad * 8]);
    bf16_8 kf1 = cat2(&ldsK[buf][(w * 16 + l16) * STR + 32 + quad * 8]);
    f32x4 ck = *(const f32x4*)(kb + j0 + w * 16 + quad * 4);
#pragma unroll
    for (int s = 0; s < 4; ++s) {
      // S^T tile: lane holds S^T[key = w*16 + quad*4 + r][q = s*16 + l16]
      f32x4 st = mfma16x16x32(kf1, qf[s][1], mfma16x16x32(kf0, qf[s][0], zero));
      f32x4 p;
#pragma unroll
      for (int r = 0; r < 4; ++r) {
        // masked key: fma -> -1.44e31, exp2 -> 0. inactive q: actq=0 -> logit 0 (= ref).
        float v = actq[s] * fmaf(st[r], SCALE2, ck[r]);
        p[r] = fast_exp2(v);
      }
      lsum[s] += p[0] + p[1] + p[2] + p[3];
      // P[q = s*16+l16][key-local = w*16 + quad*4 .. +4] -> one b64 store
      *(s16x4*)(&ldsQP[(s * 16 + l16) * STR + w * 16 + quad * 4]) = pack_bf16x4(p);
    }
    lds_barrier();  // B1: P complete across waves; K reads done (no vmcnt drain)

    // --- PV: this wave's d block (d = w*16 .. +16) vs all 64 keys ---
#pragma unroll
    for (int kc = 0; kc < 2; ++kc) {
      bf16_8 vf = cat2(&ldsV[buf][(w * 16 + l16) * STR + kc * 32 + quad * 8]);
#pragma unroll
      for (int s = 0; s < 4; ++s) {
        bf16_8 pf = cat2(&ldsQP[(s * 16 + l16) * STR + kc * 32 + quad * 8]);
        acc[s] = mfma16x16x32(pf, vf, acc[s]);
      }
    }
    // write tile t+1 into the other buffer (loads above have ~full body of slack)
    write2(&ldsK[nbuf][srow * STR + sc * 8], k0);
    write2(&ldsK[nbuf][(srow + 32) * STR + sc * 8], k1);
    write2(&ldsV[nbuf][srow * STR + sc * 8], v0);
    write2(&ldsV[nbuf][(srow + 32) * STR + sc * 8], v1);
    lds_barrier();  // B2: tile t+1 visible; P free for overwrite
  }

  // --- lsum: quad-sum in-wave, cross-wave via LDS (ldsQP reused) ---
  __syncthreads();
  float* ls = (float*)ldsQP;
#pragma unroll
  for (int s = 0; s < 4; ++s) {
    float v = lsum[s];
    v += __shfl_xor(v, 16);
    v += __shfl_xor(v, 32);
    if (quad == 0) ls[(w * 4 + s) * 16 + l16] = v;
  }
  __syncthreads();
  float lr[4][4];
#pragma unroll
  for (int s = 0; s < 4; ++s) {
    float tot = ls[(0 * 4 + s) * 16 + l16] + ls[(1 * 4 + s) * 16 + l16] +
                ls[(2 * 4 + s) * 16 + l16] + ls[(3 * 4 + s) * 16 + l16];
    float linv = 1.0f / tot;
#pragma unroll
    for (int r = 0; r < 4; ++r) lr[s][r] = __shfl(linv, quad * 4 + r);
  }
#pragma unroll
  for (int s = 0; s < 4; ++s)
#pragma unroll
    for (int r = 0; r < 4; ++r)
      out[((size_t)bz * SEQ + q0 + s * 16 + quad * 4 + r) * HID + h * HD + w * 16 + l16] =
          acc[s][r] * lr[s][r];
}

extern "C" void kernel_launch(void* const* d_in, const int* in_sizes, int n_in,
                              void* d_out, int out_size, void* d_ws, size_t ws_size,
                              hipStream_t stream) {
  (void)in_sizes; (void)n_in; (void)out_size;
  const float* toks = (const float*)d_in[0];
  const int* masks = (const int*)d_in[1];
  const float* Wq = (const float*)d_in[2];
  const float* bq = (const float*)d_in[3];
  const float* Wk = (const float*)d_in[4];
  const float* bk = (const float*)d_in[5];
  const float* Wv = (const float*)d_in[6];
  const float* bv = (const float*)d_in[7];
  char* ws = (char*)d_ws;
  const size_t KADD_B = (size_t)BATCH * SEQ * 4;
  const size_t WT_B = (size_t)HID * HID * 2;
  const size_t KV_FULL_B = (size_t)BATCH * NHEADS * SEQ * HD * 2;
  const size_t KV_HEAD_B = (size_t)BATCH * SEQ * HD * 2;
  const size_t TIER_A_NEED = KADD_B + 3 * WT_B + 2 * KV_FULL_B;  // ~28.7 MB
  float* kaddG = (float*)(ws);
  __bf16* WtQ = (__bf16*)(ws + KADD_B + 0 * WT_B);
  __bf16* WtK = (__bf16*)(ws + KADD_B + 1 * WT_B);
  __bf16* WtV = (__bf16*)(ws + KADD_B + 2 * WT_B);
  float* outp = (float*)d_out;

  mask_kadd<<<BATCH * SEQ / 256, 256, 0, stream>>>(masks, kaddG);
  dim3 tgrid(HID / 32, HID / 32, 3), tblk(32, 8);
  transpose768x3<<<tgrid, tblk, 0, stream>>>(Wq, Wk, Wv, WtQ);

  if (ws_size >= TIER_A_NEED) {
    __bf16* Kf = (__bf16*)(ws + KADD_B + 3 * WT_B);
    __bf16* Vtf = (__bf16*)(ws + KADD_B + 3 * WT_B + KV_FULL_B);
    dim3 pgrid(BATCH * SEQ / 64, NHEADS);
    proj_kv<<<pgrid, 256, 0, stream>>>(toks, WtK, bk, WtV, bv, Kf, Vtf, 0, NHEADS);
    dim3 agrid(SEQ / 64, NHEADS, BATCH);
    attn_fused<<<agrid, 256, 0, stream>>>(toks, WtQ, bq, Kf, Vtf, kaddG, outp, 0, NHEADS);
  } else {
    __bf16* Kh = (__bf16*)(ws + KADD_B + 3 * WT_B);
    __bf16* Vth = (__bf16*)(ws + KADD_B + 3 * WT_B + KV_HEAD_B);
    dim3 pgrid(BATCH * SEQ / 64, 1);
    dim3 agrid(SEQ / 64, 1, BATCH);
    for (int h = 0; h < NHEADS; ++h) {
      proj_kv<<<pgrid, 256, 0, stream>>>(toks, WtK, bk, WtV, bv, Kh, Vth, h, 1);
      attn_fused<<<agrid, 256, 0, stream>>>(toks, WtQ, bq, Kh, Vth, kaddG, outp, h, 1);
    }
  }
}